// Round 7
// baseline (521.345 us; speedup 1.0000x reference)
//
#include <hip/hip_runtime.h>
#include <math.h>

typedef unsigned short u16;
typedef __attribute__((ext_vector_type(8))) short bf16x8;
typedef __attribute__((ext_vector_type(4))) float f32x4;

#define LOG2E 1.4426950408889634f

__device__ inline u16 f2bf(float x) {
  unsigned int u = __float_as_uint(x);
  u += 0x7fffu + ((u >> 16) & 1u);
  return (u16)(u >> 16);
}
__device__ inline float bf2f(u16 h) {
  return __uint_as_float(((unsigned int)h) << 16);
}
__device__ inline float4 ld_bf4(const u16* p) {
  ushort4 v = *(const ushort4*)p;
  return make_float4(bf2f(v.x), bf2f(v.y), bf2f(v.z), bf2f(v.w));
}
__device__ inline void gload_lds16(const u16* g, char* lds) {
  __builtin_amdgcn_global_load_lds(
      (const __attribute__((address_space(1))) unsigned int*)g,
      (__attribute__((address_space(3))) unsigned int*)lds, 16, 0, 0);
}

// ---------------- setup: zero cnt + weight split + layer-1 linear + Wof fold GEMM ----------------
// lin loop interchanged (k outer): W loads stay L2-broadcast (round-15 win).
// Round 17: +256 blocks computing Wof = Wo @ fc1w_bot (head fold, stage 1).
// Round 22: linear branch re-mapped thread->8 contiguous cols of ONE row (was 1 col of
// 8 rows): stores go 16 scalar u16 -> 2 uint4 per thread (G13). Same FMA count, same
// k-ascending accumulation per output column (bit-exact).
__global__ void k_setup(int* __restrict__ cnt, int nz,
                        const float* __restrict__ W2pl, const float* __restrict__ W2pr,
                        const float* __restrict__ W2ll, const float* __restrict__ W2lr,
                        u16* __restrict__ Whp, u16* __restrict__ Wlp,
                        u16* __restrict__ Whl, u16* __restrict__ Wll_o,
                        const float* __restrict__ xp, int Kp, int Np,
                        const float* __restrict__ xl_, int Kl, int Nl,
                        const float* __restrict__ W1pl, const float* __restrict__ W1pr,
                        const float* __restrict__ W1ll, const float* __restrict__ W1lr,
                        u16* __restrict__ xlh_p, u16* __restrict__ xrh_p,
                        u16* __restrict__ xlh_l, u16* __restrict__ xrh_l,
                        int linPer,
                        const float* __restrict__ Wo, const float* __restrict__ fc1w_,
                        float* __restrict__ Wof) {
  __shared__ float xs[16][8];  // [k][r] transposed for broadcast reads (linear branch)
  __shared__ float sW[256];    // Wo row (fold branch)
  const int zb = (nz + 255) / 256;
  if ((int)blockIdx.x < zb) {
    int i = blockIdx.x * 256 + threadIdx.x;
    if (i < nz) cnt[i] = 0;
    return;
  }
  int wb = blockIdx.x - zb;
  if (wb < 1024) {  // weight split
    int n = wb & 511;
    int side = wb >> 9;
    int col = n & 255;
    int k = threadIdx.x;
    const float* W = side == 0 ? (n < 256 ? W2pl : W2pr) : (n < 256 ? W2ll : W2lr);
    float w = W[k * 256 + col];
    u16* Wh = side ? Whl : Whp;
    u16* Wlo = side ? Wll_o : Wlp;
    u16 hb = f2bf(w);
    Wh[n * 256 + k] = hb;
    Wlo[n * 256 + k] = f2bf(w - bf2f(hb));
    return;
  }
  int wb2 = wb - 1024;
  if (wb2 >= 2 * linPer) {  // head fold stage 1: Wof[m,j] = sum_c Wo[m,c]*fc1w[256+c,j]
    int row = wb2 - 2 * linPer;
    if (row >= 256) return;
    int jj = threadIdx.x;
    sW[jj] = Wo[row * 256 + jj];
    __syncthreads();
    float a0 = 0.f, a1 = 0.f, a2 = 0.f, a3 = 0.f;
    for (int c = 0; c < 256; c += 4) {
      a0 = fmaf(sW[c], fc1w_[(256 + c) * 256 + jj], a0);
      a1 = fmaf(sW[c + 1], fc1w_[(256 + c + 1) * 256 + jj], a1);
      a2 = fmaf(sW[c + 2], fc1w_[(256 + c + 2) * 256 + jj], a2);
      a3 = fmaf(sW[c + 3], fc1w_[(256 + c + 3) * 256 + jj], a3);
    }
    Wof[row * 256 + jj] = (a0 + a1) + (a2 + a3);
    return;
  }
  // layer-1 linear: k outer, thread -> (row r = j>>5, cols c8 = (j&31)*8 .. +7)
  const int side = wb2 / linPer;
  const float* x = side ? xl_ : xp;
  const int K = side ? Kl : Kp;
  const int N = side ? Nl : Np;
  const float* Wl = side ? W1ll : W1pl;
  const float* Wr = side ? W1lr : W1pr;
  u16* xlh = side ? xlh_l : xlh_p;
  u16* xrh = side ? xrh_l : xrh_p;
  int base = (wb2 - side * linPer) * 8;
  if (base >= N) return;
  int j = threadIdx.x;
  int tot = 8 * K;
  for (int i = j; i < tot; i += 256) {
    int r = i / K, k = i - r * K;
    if (base + r < N) xs[k][r] = x[(size_t)(base + r) * K + k];
  }
  __syncthreads();
  const int r = j >> 5;
  const int c8 = (j & 31) * 8;
  float al[8] = {}, ar[8] = {};
  for (int k = 0; k < K; ++k) {
    float xv = xs[k][r];
    float4 w0 = *(const float4*)&Wl[k * 256 + c8];
    float4 w1 = *(const float4*)&Wl[k * 256 + c8 + 4];
    float4 v0 = *(const float4*)&Wr[k * 256 + c8];
    float4 v1 = *(const float4*)&Wr[k * 256 + c8 + 4];
    al[0] = fmaf(xv, w0.x, al[0]); al[1] = fmaf(xv, w0.y, al[1]);
    al[2] = fmaf(xv, w0.z, al[2]); al[3] = fmaf(xv, w0.w, al[3]);
    al[4] = fmaf(xv, w1.x, al[4]); al[5] = fmaf(xv, w1.y, al[5]);
    al[6] = fmaf(xv, w1.z, al[6]); al[7] = fmaf(xv, w1.w, al[7]);
    ar[0] = fmaf(xv, v0.x, ar[0]); ar[1] = fmaf(xv, v0.y, ar[1]);
    ar[2] = fmaf(xv, v0.z, ar[2]); ar[3] = fmaf(xv, v0.w, ar[3]);
    ar[4] = fmaf(xv, v1.x, ar[4]); ar[5] = fmaf(xv, v1.y, ar[5]);
    ar[6] = fmaf(xv, v1.z, ar[6]); ar[7] = fmaf(xv, v1.w, ar[7]);
  }
  int n = base + r;
  if (n < N) {
    uint4 pl, pr;
    pl.x = (unsigned)f2bf(al[0]) | ((unsigned)f2bf(al[1]) << 16);
    pl.y = (unsigned)f2bf(al[2]) | ((unsigned)f2bf(al[3]) << 16);
    pl.z = (unsigned)f2bf(al[4]) | ((unsigned)f2bf(al[5]) << 16);
    pl.w = (unsigned)f2bf(al[6]) | ((unsigned)f2bf(al[7]) << 16);
    pr.x = (unsigned)f2bf(ar[0]) | ((unsigned)f2bf(ar[1]) << 16);
    pr.y = (unsigned)f2bf(ar[2]) | ((unsigned)f2bf(ar[3]) << 16);
    pr.z = (unsigned)f2bf(ar[4]) | ((unsigned)f2bf(ar[5]) << 16);
    pr.w = (unsigned)f2bf(ar[6]) | ((unsigned)f2bf(ar[7]) << 16);
    *(uint4*)&xlh[(size_t)n * 256 + c8] = pl;
    *(uint4*)&xrh[(size_t)n * 256 + c8] = pr;
  }
}

// ---------------- histogram (both sides) + head fold stage 2 ----------------
// Round 17: +257 blocks computing W2 = Wv @ Wof and biasEff (needs Wof from k_setup;
// stream order guarantees it).
__global__ void k_histb(const int* __restrict__ eip, int Ep, const int* __restrict__ eil,
                        int El, int* __restrict__ cntp, int* __restrict__ cntl,
                        int histB,
                        const float* __restrict__ Wv, const float* __restrict__ Wof,
                        const float* __restrict__ fc1w_, const float* __restrict__ bv,
                        const float* __restrict__ bo, const float* __restrict__ fc1b,
                        float* __restrict__ W2, float* __restrict__ biasEff) {
  __shared__ float sV[256];
  if ((int)blockIdx.x >= histB) {
    int g2 = blockIdx.x - histB;
    int jj = threadIdx.x;
    if (g2 < 256) {  // W2[k,j] = sum_m Wv[k,m]*Wof[m,j]
      sV[jj] = Wv[g2 * 256 + jj];
      __syncthreads();
      float a0 = 0.f, a1 = 0.f, a2 = 0.f, a3 = 0.f;
      for (int m = 0; m < 256; m += 4) {
        a0 = fmaf(sV[m], Wof[m * 256 + jj], a0);
        a1 = fmaf(sV[m + 1], Wof[(m + 1) * 256 + jj], a1);
        a2 = fmaf(sV[m + 2], Wof[(m + 2) * 256 + jj], a2);
        a3 = fmaf(sV[m + 3], Wof[(m + 3) * 256 + jj], a3);
      }
      W2[g2 * 256 + jj] = (a0 + a1) + (a2 + a3);
    } else {  // biasEff[j] = bv@Wof + bo@fc1w_bot + fc1b
      float acc = fc1b[jj];
      for (int k = 0; k < 256; ++k) acc = fmaf(bv[k], Wof[k * 256 + jj], acc);
      for (int k = 0; k < 256; ++k) acc = fmaf(bo[k], fc1w_[(256 + k) * 256 + jj], acc);
      biasEff[jj] = acc;
    }
    return;
  }
  int e = blockIdx.x * blockDim.x + threadIdx.x;
  if (e < Ep) atomicAdd(&cntp[eip[Ep + e]], 1);
  else if (e < Ep + El) { int e2 = e - Ep; atomicAdd(&cntl[eil[El + e2]], 1); }
}

// ---------------- per-block scan (also zeroes cur) ----------------
__global__ void k_scan1b(const int* __restrict__ cntp, int Np, const int* __restrict__ cntl,
                         int Nl, int nbp, int* __restrict__ offsp, int* __restrict__ offsl,
                         int* __restrict__ curp, int* __restrict__ curl,
                         int* __restrict__ bsum) {
  __shared__ int s[256];
  int tid = threadIdx.x;
  int side = ((int)blockIdx.x >= nbp) ? 1 : 0;
  int blk = side ? (blockIdx.x - nbp) : blockIdx.x;
  const int* cnt = side ? cntl : cntp;
  int* offs = side ? offsl : offsp;
  int* cur = side ? curl : curp;
  int N = side ? Nl : Np;
  int i = blk * 256 + tid;
  int v = (i < N) ? cnt[i] : 0;
  if (i < N) cur[i] = 0;
  s[tid] = v;
  __syncthreads();
  for (int off = 1; off < 256; off <<= 1) {
    int t = 0;
    if (tid >= off) t = s[tid - off];
    __syncthreads();
    if (tid >= off) s[tid] += t;
    __syncthreads();
  }
  if (i < N) offs[i] = s[tid] - v;
  if (tid == 255) bsum[side * 256 + blk] = s[255];
}

__global__ void k_scan2b(int* __restrict__ bsum, int nbp, int nbl) {
  __shared__ int s[256];
  int side = blockIdx.x;
  int nb = side ? nbl : nbp;
  int* bs = bsum + side * 256;
  int tid = threadIdx.x;
  int v = (tid < nb) ? bs[tid] : 0;
  s[tid] = v;
  __syncthreads();
  for (int off = 1; off < 256; off <<= 1) {
    int t = 0;
    if (tid >= off) t = s[tid - off];
    __syncthreads();
    if (tid >= off) s[tid] += t;
    __syncthreads();
  }
  if (tid < nb) bs[tid] = s[tid] - v;
}

// ---------------- fill (bsum folded in) ----------------
__global__ void k_fillb(const int* __restrict__ eip, int Ep, const int* __restrict__ eil,
                        int El, const int* __restrict__ offsp, const int* __restrict__ offsl,
                        const int* __restrict__ bsum,
                        int* __restrict__ curp, int* __restrict__ curl,
                        int* __restrict__ csrp, int* __restrict__ csrl) {
  int e = blockIdx.x * blockDim.x + threadIdx.x;
  if (e < Ep) {
    int d = eip[Ep + e];
    int pos = offsp[d] + bsum[d >> 8] + atomicAdd(&curp[d], 1);
    csrp[pos] = eip[e];
  } else if (e < Ep + El) {
    int e2 = e - Ep;
    int d = eil[El + e2];
    int pos = offsl[d] + bsum[256 + (d >> 8)] + atomicAdd(&curl[d], 1);
    csrl[pos] = eil[e2];
  }
}

// ---------------- dual GEMM, 128x128 y=4 proven shape; XCD-grouped block swizzle ----------------
// NOTE: 128x256-wide tile regressed 2x with ~3.6x HBM write amplification (rounds 6, 11).
// Round 19 (kept, +15 us): width-16 global_load_lds staging + LDS double-buffer,
// linear LDS dest + inverse-permuted global source (rule #21), 2-phase schedule.
__global__ void __launch_bounds__(256, 2) k_mm_dual_b(
    const u16* __restrict__ A_p, const u16* __restrict__ A_l,
    const u16* __restrict__ Bh_p, const u16* __restrict__ Bl_p,
    const u16* __restrict__ Bh_l, const u16* __restrict__ Bl_l,
    u16* __restrict__ XLh_p, u16* __restrict__ XRh_p,
    u16* __restrict__ XLh_l, u16* __restrict__ XRh_l, int Np, int Nl, int Rp, int Rtot) {
  __shared__ __align__(16) char smem[49152];  // 2 buffers x (sA 8K | sBh 8K | sBl 8K)
  const int gid = blockIdx.x;
  const int rblk = (gid >> 5) * 8 + (gid & 7);
  const int col = (gid >> 3) & 3;
  if (rblk >= Rtot) return;
  const int side = (rblk >= Rp) ? 1 : 0;
  const int rloc = side ? rblk - Rp : rblk;
  const u16* A = side ? A_l : A_p;
  const u16* Bhi = side ? Bh_l : Bh_p;
  const u16* Blo = side ? Bl_l : Bl_p;
  u16* XLh = side ? XLh_l : XLh_p;
  u16* XRh = side ? XRh_l : XRh_p;
  const int M = side ? Nl : Np;
  const int t = threadIdx.x;
  const int rowBase = rloc * 128;
  const int j0 = col * 128;
  const int lane = t & 63;
  const int wid = t >> 6;
  const int srow0 = wid * 32 + (lane >> 2);
  const int cL = lane & 3;
  int rA0 = rowBase + srow0;
  if (rA0 >= M) rA0 = M - 1;
  int rA1 = rowBase + srow0 + 16;
  if (rA1 >= M) rA1 = M - 1;
  const int rB0 = j0 + srow0;
  const int rB1 = j0 + srow0 + 16;
  const int c0 = (cL - ((srow0 >> 1) & 3)) & 3;
  const int c1 = (cL - (((srow0 + 16) >> 1) & 3)) & 3;
  const size_t gA0 = (size_t)rA0 * 256 + c0 * 8;
  const size_t gA1 = (size_t)rA1 * 256 + c1 * 8;
  const size_t gB0 = (size_t)rB0 * 256 + c0 * 8;
  const size_t gB1 = (size_t)rB1 * 256 + c1 * 8;
  const int seg = wid * 2048;
  const int wm = (wid & 1) * 64;
  const int wn = (wid >> 1) * 64;
  const int kq = lane >> 4;
  const int mr = lane & 15;
  int offA[4], offB[4];
#pragma unroll
  for (int i = 0; i < 4; ++i) {
    int m = wm + i * 16 + mr;
    offA[i] = m * 64 + ((kq + (m >> 1)) & 3) * 16;
    int n = wn + i * 16 + mr;
    offB[i] = n * 64 + ((kq + (n >> 1)) & 3) * 16;
  }
  f32x4 acc[4][4] = {};
  auto stage = [&](int bsel, int kt) {
    char* bb = smem + bsel * 24576;
    const int k0 = kt * 32;
    gload_lds16(A + gA0 + k0, bb + seg);
    gload_lds16(A + gA1 + k0, bb + seg + 1024);
    gload_lds16(Bhi + gB0 + k0, bb + 8192 + seg);
    gload_lds16(Bhi + gB1 + k0, bb + 8192 + seg + 1024);
    gload_lds16(Blo + gB0 + k0, bb + 16384 + seg);
    gload_lds16(Blo + gB1 + k0, bb + 16384 + seg + 1024);
  };
  stage(0, 0);
#pragma unroll
  for (int kt = 0; kt < 8; ++kt) {
    const int cur = kt & 1;
    asm volatile("s_waitcnt vmcnt(0)" ::: "memory");
    __syncthreads();  // cur buffer complete; prev buffer's reads all done
    if (kt < 7) stage(cur ^ 1, kt + 1);  // latency hides under the MFMAs below
    const char* bb = smem + cur * 24576;
    bf16x8 a[4], bh[4], bl[4];
#pragma unroll
    for (int i = 0; i < 4; ++i) {
      a[i] = *(const bf16x8*)(bb + offA[i]);
      bh[i] = *(const bf16x8*)(bb + 8192 + offB[i]);
      bl[i] = *(const bf16x8*)(bb + 16384 + offB[i]);
    }
#pragma unroll
    for (int i = 0; i < 4; ++i)
#pragma unroll
      for (int j = 0; j < 4; ++j) {
        acc[i][j] = __builtin_amdgcn_mfma_f32_16x16x32_bf16(a[i], bh[j], acc[i][j], 0, 0, 0);
        acc[i][j] = __builtin_amdgcn_mfma_f32_16x16x32_bf16(a[i], bl[j], acc[i][j], 0, 0, 0);
      }
  }
  __syncthreads();
  u16* wtile = (u16*)(smem + wid * 8192);
#pragma unroll
  for (int i = 0; i < 4; ++i)
#pragma unroll
    for (int j = 0; j < 4; ++j)
#pragma unroll
      for (int r = 0; r < 4; ++r)
        wtile[(i * 16 + kq * 4 + r) * 64 + j * 16 + mr] = f2bf(acc[i][j][r]);
  u16* cbase = (col < 2) ? XLh : XRh;
  const int cb = (col < 2) ? j0 : j0 - 256;
  const int r8 = lane >> 3;
  const int c8 = lane & 7;
#pragma unroll
  for (int rr = 0; rr < 8; ++rr) {
    int lr = rr * 8 + r8;
    uint4 v = *(const uint4*)&wtile[lr * 64 + c8 * 8];
    int row = rowBase + wm + lr;
    if (row < M) *(uint4*)&cbase[(size_t)row * 256 + cb + wn + c8 * 8] = v;
  }
}

// ---------------- GATv2 aggregation (round-14 proven: full wave, 4-acc, NO index prefetch) ----------------
// lrelu(t)*wa == t*(0.6wa) + |t|*(0.4wa) exactly; softmax shift fixed at self logit.
// att pre-scaled by log2(e) -> native v_exp_f32 via __builtin_amdgcn_exp2f.
// LEDGER — do not touch: half-wave (r13), csr prefetch (r15), U=8 unroll (r18: VGPR
// 36->44, occ 61->45%, 97->138 us), POOL atomics epilogue (r20: device-scope f32
// atomics go memory-side on non-coherent XCD L2s -> 400MB writes, 97->373 us) all
// regressed. exp2 (r17) neutral. This exact form stays.
#define GAT_DOT(a, q)                                                          \
  {                                                                            \
    float t0 = a.x + rd.x, t1 = a.y + rd.y, t2 = a.z + rd.z, t3 = a.w + rd.w;  \
    q = fmaf(t3, wa6.w, fabsf(t3) * wa4.w);                                    \
    q = fmaf(fabsf(t2), wa4.z, fmaf(t2, wa6.z, q));                            \
    q = fmaf(fabsf(t1), wa4.y, fmaf(t1, wa6.y, q));                            \
    q = fmaf(fabsf(t0), wa4.x, fmaf(t0, wa6.x, q));                            \
  }

template <int H>
__global__ void k_gat_gather_b(
    const u16* __restrict__ xlh_p, const u16* __restrict__ xrh_p, u16* __restrict__ out_p,
    const u16* __restrict__ xlh_l, const u16* __restrict__ xrh_l, u16* __restrict__ out_l,
    const int* __restrict__ csr_p, const int* __restrict__ offs_p,
    const int* __restrict__ cnt_p,
    const int* __restrict__ csr_l, const int* __restrict__ offs_l,
    const int* __restrict__ cnt_l, const int* __restrict__ bsum,
    const float* __restrict__ att_p, const float* __restrict__ bias_p,
    const float* __restrict__ att_l, const float* __restrict__ bias_l,
    int Np, int Nl) {
  const int side = blockIdx.y;
  const u16* xlh = side ? xlh_l : xlh_p;
  const u16* xrh = side ? xrh_l : xrh_p;
  u16* out = side ? out_l : out_p;
  const int* csr = side ? csr_l : csr_p;
  const int* offs = side ? offs_l : offs_p;
  const int* cnt = side ? cnt_l : cnt_p;
  const float* att = side ? att_l : att_p;
  const float* bias = side ? bias_l : bias_p;
  const int N = side ? Nl : Np;
  int d = blockIdx.x * 4 + (threadIdx.x >> 6);
  if (d >= N) return;
  const int lo4 = (threadIdx.x & 63) * 4;
  const float4 rd = ld_bf4(&xrh[(size_t)d * 256 + lo4]);
  const float4 wa = *(const float4*)&att[lo4];
  const float4 wa6 = make_float4(0.6f * LOG2E * wa.x, 0.6f * LOG2E * wa.y,
                                 0.6f * LOG2E * wa.z, 0.6f * LOG2E * wa.w);
  const float4 wa4 = make_float4(0.4f * LOG2E * wa.x, 0.4f * LOG2E * wa.y,
                                 0.4f * LOG2E * wa.z, 0.4f * LOG2E * wa.w);
  const float4 xd = ld_bf4(&xlh[(size_t)d * 256 + lo4]);
  float base;
  GAT_DOT(xd, base)
#pragma unroll
  for (int off = 1; off <= (H == 2 ? 16 : 32); off <<= 1) base += __shfl_xor(base, off, 64);
  float l0 = 1.f, l1 = 0.f, l2 = 0.f, l3 = 0.f;
  float4 acc0 = xd;
  float4 acc1 = make_float4(0.f, 0.f, 0.f, 0.f);
  float4 acc2 = make_float4(0.f, 0.f, 0.f, 0.f);
  float4 acc3 = make_float4(0.f, 0.f, 0.f, 0.f);
  const int o0 = offs[d] + bsum[side * 256 + (d >> 8)];
  const int c = cnt[d];
  int j = 0;
  for (; j + 3 < c; j += 4) {
    int s0 = csr[o0 + j], s1 = csr[o0 + j + 1], s2 = csr[o0 + j + 2], s3 = csr[o0 + j + 3];
    float4 a0 = ld_bf4(&xlh[(size_t)s0 * 256 + lo4]);
    float4 a1 = ld_bf4(&xlh[(size_t)s1 * 256 + lo4]);
    float4 a2 = ld_bf4(&xlh[(size_t)s2 * 256 + lo4]);
    float4 a3 = ld_bf4(&xlh[(size_t)s3 * 256 + lo4]);
    float q0, q1, q2, q3;
    GAT_DOT(a0, q0)
    GAT_DOT(a1, q1)
    GAT_DOT(a2, q2)
    GAT_DOT(a3, q3)
#pragma unroll
    for (int off = 1; off <= (H == 2 ? 16 : 32); off <<= 1) {
      q0 += __shfl_xor(q0, off, 64);
      q1 += __shfl_xor(q1, off, 64);
      q2 += __shfl_xor(q2, off, 64);
      q3 += __shfl_xor(q3, off, 64);
    }
    float w0 = __builtin_amdgcn_exp2f(q0 - base), w1 = __builtin_amdgcn_exp2f(q1 - base);
    float w2 = __builtin_amdgcn_exp2f(q2 - base), w3 = __builtin_amdgcn_exp2f(q3 - base);
    l0 += w0; l1 += w1; l2 += w2; l3 += w3;
    acc0.x = fmaf(w0, a0.x, acc0.x); acc0.y = fmaf(w0, a0.y, acc0.y);
    acc0.z = fmaf(w0, a0.z, acc0.z); acc0.w = fmaf(w0, a0.w, acc0.w);
    acc1.x = fmaf(w1, a1.x, acc1.x); acc1.y = fmaf(w1, a1.y, acc1.y);
    acc1.z = fmaf(w1, a1.z, acc1.z); acc1.w = fmaf(w1, a1.w, acc1.w);
    acc2.x = fmaf(w2, a2.x, acc2.x); acc2.y = fmaf(w2, a2.y, acc2.y);
    acc2.z = fmaf(w2, a2.z, acc2.z); acc2.w = fmaf(w2, a2.w, acc2.w);
    acc3.x = fmaf(w3, a3.x, acc3.x); acc3.y = fmaf(w3, a3.y, acc3.y);
    acc3.z = fmaf(w3, a3.z, acc3.z); acc3.w = fmaf(w3, a3.w, acc3.w);
  }
  for (; j < c; ++j) {
    int s0 = csr[o0 + j];
    float4 a0 = ld_bf4(&xlh[(size_t)s0 * 256 + lo4]);
    float q0;
    GAT_DOT(a0, q0)
#pragma unroll
    for (int off = 1; off <= (H == 2 ? 16 : 32); off <<= 1) q0 += __shfl_xor(q0, off, 64);
    float w0 = __builtin_amdgcn_exp2f(q0 - base);
    l0 += w0;
    acc0.x = fmaf(w0, a0.x, acc0.x); acc0.y = fmaf(w0, a0.y, acc0.y);
    acc0.z = fmaf(w0, a0.z, acc0.z); acc0.w = fmaf(w0, a0.w, acc0.w);
  }
  float inv = 1.f / (l0 + l1 + l2 + l3);
  float ax = acc0.x + acc1.x + acc2.x + acc3.x;
  float ay = acc0.y + acc1.y + acc2.y + acc3.y;
  float az = acc0.z + acc1.z + acc2.z + acc3.z;
  float aw = acc0.w + acc1.w + acc2.w + acc3.w;
  const float4 b4 = *(const float4*)&bias[lo4];
  ushort4 hv;
  hv.x = f2bf(ax * inv + b4.x);
  hv.y = f2bf(ay * inv + b4.y);
  hv.z = f2bf(az * inv + b4.z);
  hv.w = f2bf(aw * inv + b4.w);
  *(ushort4*)&out[(size_t)d * 256 + lo4] = hv;
}

// ---------------- head (round 17: algebraically folded; round 21: pool fused in) ----------------
// softmax over 1 key == identity, so attn = lxs@Wv@Wo + bv@Wo + bo is linear and
// fc1 distributes: h = px@fc1w_top + lxs@W2 + biasEff, W2/biasEff precomputed in
// k_setup/k_histb spare blocks. Round 21: k_pool_part deleted — each head block
// reads its own graph's Ah rows directly (ushort4, 4 rows in flight, LDS 4-way
// reduce; same pattern as the deleted pool kernel). NO atomics (r20 lesson).
__global__ void k_head(const u16* __restrict__ Ahp, const u16* __restrict__ Ahl,
                       const int* __restrict__ bp, int Np,
                       const int* __restrict__ bl_, int Nl,
                       const float* __restrict__ fc1w, const float* __restrict__ W2,
                       const float* __restrict__ biasEff,
                       const float* __restrict__ lng, const float* __restrict__ lnb,
                       const float* __restrict__ fc2w, const float* __restrict__ fc2b,
                       float* __restrict__ out) {
  int b = blockIdx.x;
  int t = threadIdx.x;
  int j = t & 255;
  int side = t >> 8;
  __shared__ float red[2][4][256];
  __shared__ float xs0[256], xs1[256];
  __shared__ float part[2][256];
  __shared__ float r1[256], r2[256];
  __shared__ float smu, srs;
  __shared__ int seg[4];
  if (t < 2) {
    const int* batch = t ? bl_ : bp;
    int N = t ? Nl : Np;
    int lo = 0, hi = N;
    while (lo < hi) { int mid = (lo + hi) >> 1; if (batch[mid] < b) lo = mid + 1; else hi = mid; }
    seg[t * 2] = lo;
    lo = 0; hi = N;
    while (lo < hi) { int mid = (lo + hi) >> 1; if (batch[mid] < b + 1) lo = mid + 1; else hi = mid; }
    seg[t * 2 + 1] = lo;
  }
  __syncthreads();
  {
    const u16* x = side ? Ahl : Ahp;
    const int st = seg[side * 2];
    const int en = seg[side * 2 + 1];
    const int r = (t >> 6) & 3;
    const int lane = t & 63;
    float4 acc = make_float4(0.f, 0.f, 0.f, 0.f);
    for (int n = st + r; n < en; n += 4) {
      float4 v = ld_bf4(&x[(size_t)n * 256 + lane * 4]);
      acc.x += v.x; acc.y += v.y; acc.z += v.z; acc.w += v.w;
    }
    red[side][r][lane * 4 + 0] = acc.x;
    red[side][r][lane * 4 + 1] = acc.y;
    red[side][r][lane * 4 + 2] = acc.z;
    red[side][r][lane * 4 + 3] = acc.w;
  }
  __syncthreads();
  {
    float cntf = fmaxf((float)(seg[side * 2 + 1] - seg[side * 2]), 1.f);
    float xsv = (red[side][0][j] + red[side][1][j] + red[side][2][j] + red[side][3][j]) / cntf;
    if (side == 0) xs0[j] = xsv; else xs1[j] = xsv;
  }
  __syncthreads();
  {
    const float* src = (t < 256) ? xs0 : xs1;
    const float* W = (t < 256) ? fc1w : W2;
    float a0 = 0.f, a1 = 0.f, a2 = 0.f, a3 = 0.f;
    for (int k = 0; k < 256; k += 4) {
      a0 = fmaf(src[k], W[k * 256 + j], a0);
      a1 = fmaf(src[k + 1], W[(k + 1) * 256 + j], a1);
      a2 = fmaf(src[k + 2], W[(k + 2) * 256 + j], a2);
      a3 = fmaf(src[k + 3], W[(k + 3) * 256 + j], a3);
    }
    part[t >> 8][j] = (a0 + a1) + (a2 + a3);
  }
  __syncthreads();
  float h = 0.f;
  if (t < 256) {
    h = part[0][j] + part[1][j] + biasEff[j];
    r1[j] = h;
    r2[j] = h * h;
  }
  __syncthreads();
  for (int off = 128; off > 0; off >>= 1) {
    if (t < off) { r1[t] += r1[t + off]; r2[t] += r2[t + off]; }
    __syncthreads();
  }
  if (t == 0) {
    float mu = r1[0] / 256.f;
    float var = r2[0] / 256.f - mu * mu;
    smu = mu;
    srs = 1.f / sqrtf(var + 1e-5f);
  }
  __syncthreads();
  if (t < 256) {
    float hn = (h - smu) * srs * lng[j] + lnb[j];
    hn = hn > 0.f ? hn : 0.01f * hn;
    r1[j] = hn * fc2w[j];
  }
  __syncthreads();
  for (int off = 128; off > 0; off >>= 1) {
    if (t < off) r1[t] += r1[t + off];
    __syncthreads();
  }
  if (t == 0) out[b] = r1[0] + fc2b[0];
}

extern "C" void kernel_launch(void* const* d_in, const int* in_sizes, int n_in,
                              void* d_out, int out_size, void* d_ws, size_t ws_size,
                              hipStream_t stream) {
  const float* px = (const float*)d_in[0];
  const float* lx = (const float*)d_in[1];
  const int* pei = (const int*)d_in[2];
  const int* lei = (const int*)d_in[3];
  const int* pb = (const int*)d_in[4];
  const int* lb = (const int*)d_in[5];
  const float* p1_Wl = (const float*)d_in[6];
  const float* p1_Wr = (const float*)d_in[7];
  const float* p1_att = (const float*)d_in[8];
  const float* p1_b = (const float*)d_in[9];
  const float* p2_Wl = (const float*)d_in[10];
  const float* p2_Wr = (const float*)d_in[11];
  const float* p2_att = (const float*)d_in[12];
  const float* p2_b = (const float*)d_in[13];
  const float* l1_Wl = (const float*)d_in[14];
  const float* l1_Wr = (const float*)d_in[15];
  const float* l1_att = (const float*)d_in[16];
  const float* l1_b = (const float*)d_in[17];
  const float* l2_Wl = (const float*)d_in[18];
  const float* l2_Wr = (const float*)d_in[19];
  const float* l2_att = (const float*)d_in[20];
  const float* l2_b = (const float*)d_in[21];
  const float* Wv = (const float*)d_in[26];
  const float* bv = (const float*)d_in[27];
  const float* Wo = (const float*)d_in[28];
  const float* bo = (const float*)d_in[29];
  const float* fc1w = (const float*)d_in[30];
  const float* fc1b = (const float*)d_in[31];
  const float* lng = (const float*)d_in[32];
  const float* lnb = (const float*)d_in[33];
  const float* fc2w = (const float*)d_in[34];
  const float* fc2b = (const float*)d_in[35];

  const int NPn = in_sizes[4];
  const int NLn = in_sizes[5];
  const int EPe = in_sizes[2] / 2;
  const int ELe = in_sizes[3] / 2;
  const int KP = in_sizes[0] / NPn;
  const int KL = in_sizes[1] / NLn;

  const int Nmax = NPn > NLn ? NPn : NLn;
  const int Emax = EPe > ELe ? EPe : ELe;
  size_t NF = (size_t)Nmax * 256;

  u16* XLh_p = (u16*)d_ws;
  u16* XRh_p = XLh_p + NF;
  u16* Ah_p = XRh_p + NF;
  u16* XLh_l = Ah_p + NF;
  u16* XRh_l = XLh_l + NF;
  u16* Ah_l = XRh_l + NF;
  u16* Wth = Ah_l + NF;  // 2 sides x 512*256
  u16* Wtl = Wth + 2 * 512 * 256;
  int* cnt = (int*)(Wtl + 2 * 512 * 256);
  int* cur = cnt + 2 * (size_t)Nmax;
  int* offs = cur + 2 * (size_t)Nmax;
  int* bsum = offs + 2 * (size_t)Nmax;
  int* csr = bsum + 512;
  int* cnt_l = cnt + Nmax;
  int* cur_l = cur + Nmax;
  int* offs_l = offs + Nmax;
  int* csr_l = csr + Emax;
  float* Wof = (float*)(csr + 2 * (size_t)Emax);  // 256x256 fold buffers
  float* W2f = Wof + 65536;
  float* bEff = W2f + 65536;

  const int nbp = (NPn + 255) / 256;
  const int nbl = (NLn + 255) / 256;
  const int nz = 2 * Nmax;
  const int zb = (nz + 255) / 256;
  const int linPer = (Nmax + 7) / 8;
  const int histB = (EPe + ELe + 255) / 256;

  // setup: zero cnt + weight split + layer-1 linear + fold stage 1 (fused)
  k_setup<<<zb + 1024 + 2 * linPer + 256, 256, 0, stream>>>(
      cnt, nz, p2_Wl, p2_Wr, l2_Wl, l2_Wr,
      Wth, Wtl, Wth + 512 * 256, Wtl + 512 * 256,
      px, KP, NPn, lx, KL, NLn, p1_Wl, p1_Wr, l1_Wl, l1_Wr,
      XLh_p, XRh_p, XLh_l, XRh_l, linPer, Wo, fc1w, Wof);
  // CSR build (+ fold stage 2)
  k_histb<<<histB + 257, 256, 0, stream>>>(pei, EPe, lei, ELe, cnt, cnt_l, histB,
                                           Wv, Wof, fc1w, bv, bo, fc1b, W2f, bEff);
  k_scan1b<<<nbp + nbl, 256, 0, stream>>>(cnt, NPn, cnt_l, NLn, nbp, offs, offs_l,
                                          cur, cur_l, bsum);
  k_scan2b<<<2, 256, 0, stream>>>(bsum, nbp, nbl);
  k_fillb<<<(EPe + ELe + 255) / 256, 256, 0, stream>>>(pei, EPe, lei, ELe, offs, offs_l,
                                                       bsum, cur, cur_l, csr, csr_l);
  // layer 1 gather
  k_gat_gather_b<2><<<dim3((Nmax + 3) / 4, 2), 256, 0, stream>>>(
      XLh_p, XRh_p, Ah_p, XLh_l, XRh_l, Ah_l,
      csr, offs, cnt, csr_l, offs_l, cnt_l, bsum,
      p1_att, p1_b, l1_att, l1_b, NPn, NLn);
  // layer 2 GEMM (XCD-grouped swizzle)
  {
    const int Rp = (NPn + 127) / 128;
    const int Rl = (NLn + 127) / 128;
    const int Rtot = Rp + Rl;
    k_mm_dual_b<<<32 * ((Rtot + 7) / 8), 256, 0, stream>>>(
        Ah_p, Ah_l, Wth, Wtl, Wth + 512 * 256, Wtl + 512 * 256,
        XLh_p, XRh_p, XLh_l, XRh_l, NPn, NLn, Rp, Rtot);
  }
  // layer 2 gather
  k_gat_gather_b<1><<<dim3((Nmax + 3) / 4, 2), 256, 0, stream>>>(
      XLh_p, XRh_p, Ah_p, XLh_l, XRh_l, Ah_l,
      csr, offs, cnt, csr_l, offs_l, cnt_l, bsum,
      p2_att, p2_b, l2_att, l2_b, NPn, NLn);
  // head (pool fused: reads Ah segments directly)
  k_head<<<256, 512, 0, stream>>>(Ah_p, Ah_l, pb, NPn, lb, NLn,
                                  fc1w, W2f, bEff, lng, lnb, fc2w, fc2b,
                                  (float*)d_out);
  (void)n_in; (void)out_size; (void)ws_size;
}

// Round 8
// 494.517 us; speedup vs baseline: 1.0543x; 1.0543x over previous
//
#include <hip/hip_runtime.h>
#include <math.h>

typedef unsigned short u16;
typedef __attribute__((ext_vector_type(8))) short bf16x8;
typedef __attribute__((ext_vector_type(4))) float f32x4;

#define LOG2E 1.4426950408889634f

__device__ inline u16 f2bf(float x) {
  unsigned int u = __float_as_uint(x);
  u += 0x7fffu + ((u >> 16) & 1u);
  return (u16)(u >> 16);
}
__device__ inline float bf2f(u16 h) {
  return __uint_as_float(((unsigned int)h) << 16);
}
__device__ inline float4 ld_bf4(const u16* p) {
  ushort4 v = *(const ushort4*)p;
  return make_float4(bf2f(v.x), bf2f(v.y), bf2f(v.z), bf2f(v.w));
}
__device__ inline void gload_lds16(const u16* g, char* lds) {
  __builtin_amdgcn_global_load_lds(
      (const __attribute__((address_space(1))) unsigned int*)g,
      (__attribute__((address_space(3))) unsigned int*)lds, 16, 0, 0);
}

// ---------------- setup: zero cnt + weight split + layer-1 linear + Wof fold GEMM ----------------
// lin loop interchanged (k outer): 20 W-loads + 160 FMAs per thread (round-15 win, ~55 us).
// Round 17: +256 blocks computing Wof = Wo @ fc1w_bot (head fold, stage 1).
// LEDGER r22: thread->8-cols remap REGRESSED +22us (W rows re-loaded 8x/block; old
// scalar stores were already lane-coalesced 128B/inst). This round-15 form is frozen.
__global__ void k_setup(int* __restrict__ cnt, int nz,
                        const float* __restrict__ W2pl, const float* __restrict__ W2pr,
                        const float* __restrict__ W2ll, const float* __restrict__ W2lr,
                        u16* __restrict__ Whp, u16* __restrict__ Wlp,
                        u16* __restrict__ Whl, u16* __restrict__ Wll_o,
                        const float* __restrict__ xp, int Kp, int Np,
                        const float* __restrict__ xl_, int Kl, int Nl,
                        const float* __restrict__ W1pl, const float* __restrict__ W1pr,
                        const float* __restrict__ W1ll, const float* __restrict__ W1lr,
                        u16* __restrict__ xlh_p, u16* __restrict__ xrh_p,
                        u16* __restrict__ xlh_l, u16* __restrict__ xrh_l,
                        int linPer,
                        const float* __restrict__ Wo, const float* __restrict__ fc1w_,
                        float* __restrict__ Wof) {
  __shared__ float xs[16][8];  // [k][r] transposed for broadcast reads (linear branch)
  __shared__ float sW[256];    // Wo row (fold branch)
  const int zb = (nz + 255) / 256;
  if ((int)blockIdx.x < zb) {
    int i = blockIdx.x * 256 + threadIdx.x;
    if (i < nz) cnt[i] = 0;
    return;
  }
  int wb = blockIdx.x - zb;
  if (wb < 1024) {  // weight split
    int n = wb & 511;
    int side = wb >> 9;
    int col = n & 255;
    int k = threadIdx.x;
    const float* W = side == 0 ? (n < 256 ? W2pl : W2pr) : (n < 256 ? W2ll : W2lr);
    float w = W[k * 256 + col];
    u16* Wh = side ? Whl : Whp;
    u16* Wlo = side ? Wll_o : Wlp;
    u16 hb = f2bf(w);
    Wh[n * 256 + k] = hb;
    Wlo[n * 256 + k] = f2bf(w - bf2f(hb));
    return;
  }
  int wb2 = wb - 1024;
  if (wb2 >= 2 * linPer) {  // head fold stage 1: Wof[m,j] = sum_c Wo[m,c]*fc1w[256+c,j]
    int row = wb2 - 2 * linPer;
    if (row >= 256) return;
    int jj = threadIdx.x;
    sW[jj] = Wo[row * 256 + jj];
    __syncthreads();
    float a0 = 0.f, a1 = 0.f, a2 = 0.f, a3 = 0.f;
    for (int c = 0; c < 256; c += 4) {
      a0 = fmaf(sW[c], fc1w_[(256 + c) * 256 + jj], a0);
      a1 = fmaf(sW[c + 1], fc1w_[(256 + c + 1) * 256 + jj], a1);
      a2 = fmaf(sW[c + 2], fc1w_[(256 + c + 2) * 256 + jj], a2);
      a3 = fmaf(sW[c + 3], fc1w_[(256 + c + 3) * 256 + jj], a3);
    }
    Wof[row * 256 + jj] = (a0 + a1) + (a2 + a3);
    return;
  }
  // layer-1 linear: k outer (W loaded once per k), 8-row accumulators inner
  const int side = wb2 / linPer;
  const float* x = side ? xl_ : xp;
  const int K = side ? Kl : Kp;
  const int N = side ? Nl : Np;
  const float* Wl = side ? W1ll : W1pl;
  const float* Wr = side ? W1lr : W1pr;
  u16* xlh = side ? xlh_l : xlh_p;
  u16* xrh = side ? xrh_l : xrh_p;
  int base = (wb2 - side * linPer) * 8;
  if (base >= N) return;
  int j = threadIdx.x;
  int tot = 8 * K;
  for (int i = j; i < tot; i += 256) {
    int r = i / K, k = i - r * K;
    if (base + r < N) xs[k][r] = x[(size_t)(base + r) * K + k];
  }
  __syncthreads();
  float al[8] = {}, ar[8] = {};
  for (int k = 0; k < K; ++k) {
    float wl = Wl[k * 256 + j];
    float wr = Wr[k * 256 + j];
#pragma unroll
    for (int r = 0; r < 8; ++r) {
      al[r] = fmaf(xs[k][r], wl, al[r]);
      ar[r] = fmaf(xs[k][r], wr, ar[r]);
    }
  }
#pragma unroll
  for (int r = 0; r < 8; ++r) {
    int n = base + r;
    if (n < N) {
      xlh[(size_t)n * 256 + j] = f2bf(al[r]);
      xrh[(size_t)n * 256 + j] = f2bf(ar[r]);
    }
  }
}

// ---------------- histogram (both sides) + head fold stage 2 ----------------
// Round 17: +257 blocks computing W2 = Wv @ Wof and biasEff (needs Wof from k_setup;
// stream order guarantees it).
__global__ void k_histb(const int* __restrict__ eip, int Ep, const int* __restrict__ eil,
                        int El, int* __restrict__ cntp, int* __restrict__ cntl,
                        int histB,
                        const float* __restrict__ Wv, const float* __restrict__ Wof,
                        const float* __restrict__ fc1w_, const float* __restrict__ bv,
                        const float* __restrict__ bo, const float* __restrict__ fc1b,
                        float* __restrict__ W2, float* __restrict__ biasEff) {
  __shared__ float sV[256];
  if ((int)blockIdx.x >= histB) {
    int g2 = blockIdx.x - histB;
    int jj = threadIdx.x;
    if (g2 < 256) {  // W2[k,j] = sum_m Wv[k,m]*Wof[m,j]
      sV[jj] = Wv[g2 * 256 + jj];
      __syncthreads();
      float a0 = 0.f, a1 = 0.f, a2 = 0.f, a3 = 0.f;
      for (int m = 0; m < 256; m += 4) {
        a0 = fmaf(sV[m], Wof[m * 256 + jj], a0);
        a1 = fmaf(sV[m + 1], Wof[(m + 1) * 256 + jj], a1);
        a2 = fmaf(sV[m + 2], Wof[(m + 2) * 256 + jj], a2);
        a3 = fmaf(sV[m + 3], Wof[(m + 3) * 256 + jj], a3);
      }
      W2[g2 * 256 + jj] = (a0 + a1) + (a2 + a3);
    } else {  // biasEff[j] = bv@Wof + bo@fc1w_bot + fc1b
      float acc = fc1b[jj];
      for (int k = 0; k < 256; ++k) acc = fmaf(bv[k], Wof[k * 256 + jj], acc);
      for (int k = 0; k < 256; ++k) acc = fmaf(bo[k], fc1w_[(256 + k) * 256 + jj], acc);
      biasEff[jj] = acc;
    }
    return;
  }
  int e = blockIdx.x * blockDim.x + threadIdx.x;
  if (e < Ep) atomicAdd(&cntp[eip[Ep + e]], 1);
  else if (e < Ep + El) { int e2 = e - Ep; atomicAdd(&cntl[eil[El + e2]], 1); }
}

// ---------------- per-block scan (also zeroes cur) ----------------
__global__ void k_scan1b(const int* __restrict__ cntp, int Np, const int* __restrict__ cntl,
                         int Nl, int nbp, int* __restrict__ offsp, int* __restrict__ offsl,
                         int* __restrict__ curp, int* __restrict__ curl,
                         int* __restrict__ bsum) {
  __shared__ int s[256];
  int tid = threadIdx.x;
  int side = ((int)blockIdx.x >= nbp) ? 1 : 0;
  int blk = side ? (blockIdx.x - nbp) : blockIdx.x;
  const int* cnt = side ? cntl : cntp;
  int* offs = side ? offsl : offsp;
  int* cur = side ? curl : curp;
  int N = side ? Nl : Np;
  int i = blk * 256 + tid;
  int v = (i < N) ? cnt[i] : 0;
  if (i < N) cur[i] = 0;
  s[tid] = v;
  __syncthreads();
  for (int off = 1; off < 256; off <<= 1) {
    int t = 0;
    if (tid >= off) t = s[tid - off];
    __syncthreads();
    if (tid >= off) s[tid] += t;
    __syncthreads();
  }
  if (i < N) offs[i] = s[tid] - v;
  if (tid == 255) bsum[side * 256 + blk] = s[255];
}

__global__ void k_scan2b(int* __restrict__ bsum, int nbp, int nbl) {
  __shared__ int s[256];
  int side = blockIdx.x;
  int nb = side ? nbl : nbp;
  int* bs = bsum + side * 256;
  int tid = threadIdx.x;
  int v = (tid < nb) ? bs[tid] : 0;
  s[tid] = v;
  __syncthreads();
  for (int off = 1; off < 256; off <<= 1) {
    int t = 0;
    if (tid >= off) t = s[tid - off];
    __syncthreads();
    if (tid >= off) s[tid] += t;
    __syncthreads();
  }
  if (tid < nb) bs[tid] = s[tid] - v;
}

// ---------------- fill (bsum folded in) ----------------
__global__ void k_fillb(const int* __restrict__ eip, int Ep, const int* __restrict__ eil,
                        int El, const int* __restrict__ offsp, const int* __restrict__ offsl,
                        const int* __restrict__ bsum,
                        int* __restrict__ curp, int* __restrict__ curl,
                        int* __restrict__ csrp, int* __restrict__ csrl) {
  int e = blockIdx.x * blockDim.x + threadIdx.x;
  if (e < Ep) {
    int d = eip[Ep + e];
    int pos = offsp[d] + bsum[d >> 8] + atomicAdd(&curp[d], 1);
    csrp[pos] = eip[e];
  } else if (e < Ep + El) {
    int e2 = e - Ep;
    int d = eil[El + e2];
    int pos = offsl[d] + bsum[256 + (d >> 8)] + atomicAdd(&curl[d], 1);
    csrl[pos] = eil[e2];
  }
}

// ---------------- dual GEMM, 128x128 y=4 proven shape; XCD-grouped block swizzle ----------------
// NOTE: 128x256-wide tile regressed 2x with ~3.6x HBM write amplification (rounds 6, 11).
// Round 19 (kept, +15 us): width-16 global_load_lds staging + LDS double-buffer,
// linear LDS dest + inverse-permuted global source (rule #21), 2-phase schedule.
__global__ void __launch_bounds__(256, 2) k_mm_dual_b(
    const u16* __restrict__ A_p, const u16* __restrict__ A_l,
    const u16* __restrict__ Bh_p, const u16* __restrict__ Bl_p,
    const u16* __restrict__ Bh_l, const u16* __restrict__ Bl_l,
    u16* __restrict__ XLh_p, u16* __restrict__ XRh_p,
    u16* __restrict__ XLh_l, u16* __restrict__ XRh_l, int Np, int Nl, int Rp, int Rtot) {
  __shared__ __align__(16) char smem[49152];  // 2 buffers x (sA 8K | sBh 8K | sBl 8K)
  const int gid = blockIdx.x;
  const int rblk = (gid >> 5) * 8 + (gid & 7);
  const int col = (gid >> 3) & 3;
  if (rblk >= Rtot) return;
  const int side = (rblk >= Rp) ? 1 : 0;
  const int rloc = side ? rblk - Rp : rblk;
  const u16* A = side ? A_l : A_p;
  const u16* Bhi = side ? Bh_l : Bh_p;
  const u16* Blo = side ? Bl_l : Bl_p;
  u16* XLh = side ? XLh_l : XLh_p;
  u16* XRh = side ? XRh_l : XRh_p;
  const int M = side ? Nl : Np;
  const int t = threadIdx.x;
  const int rowBase = rloc * 128;
  const int j0 = col * 128;
  const int lane = t & 63;
  const int wid = t >> 6;
  const int srow0 = wid * 32 + (lane >> 2);
  const int cL = lane & 3;
  int rA0 = rowBase + srow0;
  if (rA0 >= M) rA0 = M - 1;
  int rA1 = rowBase + srow0 + 16;
  if (rA1 >= M) rA1 = M - 1;
  const int rB0 = j0 + srow0;
  const int rB1 = j0 + srow0 + 16;
  const int c0 = (cL - ((srow0 >> 1) & 3)) & 3;
  const int c1 = (cL - (((srow0 + 16) >> 1) & 3)) & 3;
  const size_t gA0 = (size_t)rA0 * 256 + c0 * 8;
  const size_t gA1 = (size_t)rA1 * 256 + c1 * 8;
  const size_t gB0 = (size_t)rB0 * 256 + c0 * 8;
  const size_t gB1 = (size_t)rB1 * 256 + c1 * 8;
  const int seg = wid * 2048;
  const int wm = (wid & 1) * 64;
  const int wn = (wid >> 1) * 64;
  const int kq = lane >> 4;
  const int mr = lane & 15;
  int offA[4], offB[4];
#pragma unroll
  for (int i = 0; i < 4; ++i) {
    int m = wm + i * 16 + mr;
    offA[i] = m * 64 + ((kq + (m >> 1)) & 3) * 16;
    int n = wn + i * 16 + mr;
    offB[i] = n * 64 + ((kq + (n >> 1)) & 3) * 16;
  }
  f32x4 acc[4][4] = {};
  auto stage = [&](int bsel, int kt) {
    char* bb = smem + bsel * 24576;
    const int k0 = kt * 32;
    gload_lds16(A + gA0 + k0, bb + seg);
    gload_lds16(A + gA1 + k0, bb + seg + 1024);
    gload_lds16(Bhi + gB0 + k0, bb + 8192 + seg);
    gload_lds16(Bhi + gB1 + k0, bb + 8192 + seg + 1024);
    gload_lds16(Blo + gB0 + k0, bb + 16384 + seg);
    gload_lds16(Blo + gB1 + k0, bb + 16384 + seg + 1024);
  };
  stage(0, 0);
#pragma unroll
  for (int kt = 0; kt < 8; ++kt) {
    const int cur = kt & 1;
    asm volatile("s_waitcnt vmcnt(0)" ::: "memory");
    __syncthreads();  // cur buffer complete; prev buffer's reads all done
    if (kt < 7) stage(cur ^ 1, kt + 1);  // latency hides under the MFMAs below
    const char* bb = smem + cur * 24576;
    bf16x8 a[4], bh[4], bl[4];
#pragma unroll
    for (int i = 0; i < 4; ++i) {
      a[i] = *(const bf16x8*)(bb + offA[i]);
      bh[i] = *(const bf16x8*)(bb + 8192 + offB[i]);
      bl[i] = *(const bf16x8*)(bb + 16384 + offB[i]);
    }
#pragma unroll
    for (int i = 0; i < 4; ++i)
#pragma unroll
      for (int j = 0; j < 4; ++j) {
        acc[i][j] = __builtin_amdgcn_mfma_f32_16x16x32_bf16(a[i], bh[j], acc[i][j], 0, 0, 0);
        acc[i][j] = __builtin_amdgcn_mfma_f32_16x16x32_bf16(a[i], bl[j], acc[i][j], 0, 0, 0);
      }
  }
  __syncthreads();
  u16* wtile = (u16*)(smem + wid * 8192);
#pragma unroll
  for (int i = 0; i < 4; ++i)
#pragma unroll
    for (int j = 0; j < 4; ++j)
#pragma unroll
      for (int r = 0; r < 4; ++r)
        wtile[(i * 16 + kq * 4 + r) * 64 + j * 16 + mr] = f2bf(acc[i][j][r]);
  u16* cbase = (col < 2) ? XLh : XRh;
  const int cb = (col < 2) ? j0 : j0 - 256;
  const int r8 = lane >> 3;
  const int c8 = lane & 7;
#pragma unroll
  for (int rr = 0; rr < 8; ++rr) {
    int lr = rr * 8 + r8;
    uint4 v = *(const uint4*)&wtile[lr * 64 + c8 * 8];
    int row = rowBase + wm + lr;
    if (row < M) *(uint4*)&cbase[(size_t)row * 256 + cb + wn + c8 * 8] = v;
  }
}

// ---------------- GATv2 aggregation (round-14 proven: full wave, 4-acc, NO index prefetch) ----------------
// lrelu(t)*wa == t*(0.6wa) + |t|*(0.4wa) exactly; softmax shift fixed at self logit.
// att pre-scaled by log2(e) -> native v_exp_f32 via __builtin_amdgcn_exp2f.
// LEDGER — loop body frozen: half-wave (r13), csr prefetch (r15), U=8 unroll (r18),
// POOL atomics epilogue (r20: 400MB HBM writes) all regressed. exp2 (r17) neutral.
// Round 23: XCD-aware bijective block swizzle (T1/m204) on blockIdx.x ONLY — nodes are
// graph-sorted so consecutive d-quads share source-row regions (~100KB/graph, L2-fits);
// round-robin dispatch was duplicating those regions across all 8 XCD L2s. Body untouched.
#define GAT_DOT(a, q)                                                          \
  {                                                                            \
    float t0 = a.x + rd.x, t1 = a.y + rd.y, t2 = a.z + rd.z, t3 = a.w + rd.w;  \
    q = fmaf(t3, wa6.w, fabsf(t3) * wa4.w);                                    \
    q = fmaf(fabsf(t2), wa4.z, fmaf(t2, wa6.z, q));                            \
    q = fmaf(fabsf(t1), wa4.y, fmaf(t1, wa6.y, q));                            \
    q = fmaf(fabsf(t0), wa4.x, fmaf(t0, wa6.x, q));                            \
  }

template <int H>
__global__ void k_gat_gather_b(
    const u16* __restrict__ xlh_p, const u16* __restrict__ xrh_p, u16* __restrict__ out_p,
    const u16* __restrict__ xlh_l, const u16* __restrict__ xrh_l, u16* __restrict__ out_l,
    const int* __restrict__ csr_p, const int* __restrict__ offs_p,
    const int* __restrict__ cnt_p,
    const int* __restrict__ csr_l, const int* __restrict__ offs_l,
    const int* __restrict__ cnt_l, const int* __restrict__ bsum,
    const float* __restrict__ att_p, const float* __restrict__ bias_p,
    const float* __restrict__ att_l, const float* __restrict__ bias_l,
    int Np, int Nl) {
  const int side = blockIdx.y;
  const u16* xlh = side ? xlh_l : xlh_p;
  const u16* xrh = side ? xrh_l : xrh_p;
  u16* out = side ? out_l : out_p;
  const int* csr = side ? csr_l : csr_p;
  const int* offs = side ? offs_l : offs_p;
  const int* cnt = side ? cnt_l : cnt_p;
  const float* att = side ? att_l : att_p;
  const float* bias = side ? bias_l : bias_p;
  const int N = side ? Nl : Np;
  // XCD-aware bijective swizzle (m204): each XCD gets a contiguous d-chunk.
  const int nwg = gridDim.x;
  const int q8 = nwg >> 3, rm = nwg & 7;
  const int xcd = blockIdx.x & 7, idx = blockIdx.x >> 3;
  const int bsw = (xcd < rm) ? (xcd * (q8 + 1) + idx)
                             : (rm * (q8 + 1) + (xcd - rm) * q8 + idx);
  int d = bsw * 4 + (threadIdx.x >> 6);
  if (d >= N) return;
  const int lo4 = (threadIdx.x & 63) * 4;
  const float4 rd = ld_bf4(&xrh[(size_t)d * 256 + lo4]);
  const float4 wa = *(const float4*)&att[lo4];
  const float4 wa6 = make_float4(0.6f * LOG2E * wa.x, 0.6f * LOG2E * wa.y,
                                 0.6f * LOG2E * wa.z, 0.6f * LOG2E * wa.w);
  const float4 wa4 = make_float4(0.4f * LOG2E * wa.x, 0.4f * LOG2E * wa.y,
                                 0.4f * LOG2E * wa.z, 0.4f * LOG2E * wa.w);
  const float4 xd = ld_bf4(&xlh[(size_t)d * 256 + lo4]);
  float base;
  GAT_DOT(xd, base)
#pragma unroll
  for (int off = 1; off <= (H == 2 ? 16 : 32); off <<= 1) base += __shfl_xor(base, off, 64);
  float l0 = 1.f, l1 = 0.f, l2 = 0.f, l3 = 0.f;
  float4 acc0 = xd;
  float4 acc1 = make_float4(0.f, 0.f, 0.f, 0.f);
  float4 acc2 = make_float4(0.f, 0.f, 0.f, 0.f);
  float4 acc3 = make_float4(0.f, 0.f, 0.f, 0.f);
  const int o0 = offs[d] + bsum[side * 256 + (d >> 8)];
  const int c = cnt[d];
  int j = 0;
  for (; j + 3 < c; j += 4) {
    int s0 = csr[o0 + j], s1 = csr[o0 + j + 1], s2 = csr[o0 + j + 2], s3 = csr[o0 + j + 3];
    float4 a0 = ld_bf4(&xlh[(size_t)s0 * 256 + lo4]);
    float4 a1 = ld_bf4(&xlh[(size_t)s1 * 256 + lo4]);
    float4 a2 = ld_bf4(&xlh[(size_t)s2 * 256 + lo4]);
    float4 a3 = ld_bf4(&xlh[(size_t)s3 * 256 + lo4]);
    float q0, q1, q2, q3;
    GAT_DOT(a0, q0)
    GAT_DOT(a1, q1)
    GAT_DOT(a2, q2)
    GAT_DOT(a3, q3)
#pragma unroll
    for (int off = 1; off <= (H == 2 ? 16 : 32); off <<= 1) {
      q0 += __shfl_xor(q0, off, 64);
      q1 += __shfl_xor(q1, off, 64);
      q2 += __shfl_xor(q2, off, 64);
      q3 += __shfl_xor(q3, off, 64);
    }
    float w0 = __builtin_amdgcn_exp2f(q0 - base), w1 = __builtin_amdgcn_exp2f(q1 - base);
    float w2 = __builtin_amdgcn_exp2f(q2 - base), w3 = __builtin_amdgcn_exp2f(q3 - base);
    l0 += w0; l1 += w1; l2 += w2; l3 += w3;
    acc0.x = fmaf(w0, a0.x, acc0.x); acc0.y = fmaf(w0, a0.y, acc0.y);
    acc0.z = fmaf(w0, a0.z, acc0.z); acc0.w = fmaf(w0, a0.w, acc0.w);
    acc1.x = fmaf(w1, a1.x, acc1.x); acc1.y = fmaf(w1, a1.y, acc1.y);
    acc1.z = fmaf(w1, a1.z, acc1.z); acc1.w = fmaf(w1, a1.w, acc1.w);
    acc2.x = fmaf(w2, a2.x, acc2.x); acc2.y = fmaf(w2, a2.y, acc2.y);
    acc2.z = fmaf(w2, a2.z, acc2.z); acc2.w = fmaf(w2, a2.w, acc2.w);
    acc3.x = fmaf(w3, a3.x, acc3.x); acc3.y = fmaf(w3, a3.y, acc3.y);
    acc3.z = fmaf(w3, a3.z, acc3.z); acc3.w = fmaf(w3, a3.w, acc3.w);
  }
  for (; j < c; ++j) {
    int s0 = csr[o0 + j];
    float4 a0 = ld_bf4(&xlh[(size_t)s0 * 256 + lo4]);
    float q0;
    GAT_DOT(a0, q0)
#pragma unroll
    for (int off = 1; off <= (H == 2 ? 16 : 32); off <<= 1) q0 += __shfl_xor(q0, off, 64);
    float w0 = __builtin_amdgcn_exp2f(q0 - base);
    l0 += w0;
    acc0.x = fmaf(w0, a0.x, acc0.x); acc0.y = fmaf(w0, a0.y, acc0.y);
    acc0.z = fmaf(w0, a0.z, acc0.z); acc0.w = fmaf(w0, a0.w, acc0.w);
  }
  float inv = 1.f / (l0 + l1 + l2 + l3);
  float ax = acc0.x + acc1.x + acc2.x + acc3.x;
  float ay = acc0.y + acc1.y + acc2.y + acc3.y;
  float az = acc0.z + acc1.z + acc2.z + acc3.z;
  float aw = acc0.w + acc1.w + acc2.w + acc3.w;
  const float4 b4 = *(const float4*)&bias[lo4];
  ushort4 hv;
  hv.x = f2bf(ax * inv + b4.x);
  hv.y = f2bf(ay * inv + b4.y);
  hv.z = f2bf(az * inv + b4.z);
  hv.w = f2bf(aw * inv + b4.w);
  *(ushort4*)&out[(size_t)d * 256 + lo4] = hv;
}

// ---------------- head (round 17: algebraically folded; round 21: pool fused in) ----------------
// softmax over 1 key == identity, so attn = lxs@Wv@Wo + bv@Wo + bo is linear and
// fc1 distributes: h = px@fc1w_top + lxs@W2 + biasEff, W2/biasEff precomputed in
// k_setup/k_histb spare blocks. Round 21: k_pool_part deleted — each head block
// reads its own graph's Ah rows directly (ushort4, 4 rows in flight, LDS 4-way
// reduce; same pattern as the deleted pool kernel). NO atomics (r20 lesson).
__global__ void k_head(const u16* __restrict__ Ahp, const u16* __restrict__ Ahl,
                       const int* __restrict__ bp, int Np,
                       const int* __restrict__ bl_, int Nl,
                       const float* __restrict__ fc1w, const float* __restrict__ W2,
                       const float* __restrict__ biasEff,
                       const float* __restrict__ lng, const float* __restrict__ lnb,
                       const float* __restrict__ fc2w, const float* __restrict__ fc2b,
                       float* __restrict__ out) {
  int b = blockIdx.x;
  int t = threadIdx.x;
  int j = t & 255;
  int side = t >> 8;
  __shared__ float red[2][4][256];
  __shared__ float xs0[256], xs1[256];
  __shared__ float part[2][256];
  __shared__ float r1[256], r2[256];
  __shared__ float smu, srs;
  __shared__ int seg[4];
  if (t < 2) {
    const int* batch = t ? bl_ : bp;
    int N = t ? Nl : Np;
    int lo = 0, hi = N;
    while (lo < hi) { int mid = (lo + hi) >> 1; if (batch[mid] < b) lo = mid + 1; else hi = mid; }
    seg[t * 2] = lo;
    lo = 0; hi = N;
    while (lo < hi) { int mid = (lo + hi) >> 1; if (batch[mid] < b + 1) lo = mid + 1; else hi = mid; }
    seg[t * 2 + 1] = lo;
  }
  __syncthreads();
  {
    const u16* x = side ? Ahl : Ahp;
    const int st = seg[side * 2];
    const int en = seg[side * 2 + 1];
    const int r = (t >> 6) & 3;
    const int lane = t & 63;
    float4 acc = make_float4(0.f, 0.f, 0.f, 0.f);
    for (int n = st + r; n < en; n += 4) {
      float4 v = ld_bf4(&x[(size_t)n * 256 + lane * 4]);
      acc.x += v.x; acc.y += v.y; acc.z += v.z; acc.w += v.w;
    }
    red[side][r][lane * 4 + 0] = acc.x;
    red[side][r][lane * 4 + 1] = acc.y;
    red[side][r][lane * 4 + 2] = acc.z;
    red[side][r][lane * 4 + 3] = acc.w;
  }
  __syncthreads();
  {
    float cntf = fmaxf((float)(seg[side * 2 + 1] - seg[side * 2]), 1.f);
    float xsv = (red[side][0][j] + red[side][1][j] + red[side][2][j] + red[side][3][j]) / cntf;
    if (side == 0) xs0[j] = xsv; else xs1[j] = xsv;
  }
  __syncthreads();
  {
    const float* src = (t < 256) ? xs0 : xs1;
    const float* W = (t < 256) ? fc1w : W2;
    float a0 = 0.f, a1 = 0.f, a2 = 0.f, a3 = 0.f;
    for (int k = 0; k < 256; k += 4) {
      a0 = fmaf(src[k], W[k * 256 + j], a0);
      a1 = fmaf(src[k + 1], W[(k + 1) * 256 + j], a1);
      a2 = fmaf(src[k + 2], W[(k + 2) * 256 + j], a2);
      a3 = fmaf(src[k + 3], W[(k + 3) * 256 + j], a3);
    }
    part[t >> 8][j] = (a0 + a1) + (a2 + a3);
  }
  __syncthreads();
  float h = 0.f;
  if (t < 256) {
    h = part[0][j] + part[1][j] + biasEff[j];
    r1[j] = h;
    r2[j] = h * h;
  }
  __syncthreads();
  for (int off = 128; off > 0; off >>= 1) {
    if (t < off) { r1[t] += r1[t + off]; r2[t] += r2[t + off]; }
    __syncthreads();
  }
  if (t == 0) {
    float mu = r1[0] / 256.f;
    float var = r2[0] / 256.f - mu * mu;
    smu = mu;
    srs = 1.f / sqrtf(var + 1e-5f);
  }
  __syncthreads();
  if (t < 256) {
    float hn = (h - smu) * srs * lng[j] + lnb[j];
    hn = hn > 0.f ? hn : 0.01f * hn;
    r1[j] = hn * fc2w[j];
  }
  __syncthreads();
  for (int off = 128; off > 0; off >>= 1) {
    if (t < off) r1[t] += r1[t + off];
    __syncthreads();
  }
  if (t == 0) out[b] = r1[0] + fc2b[0];
}

extern "C" void kernel_launch(void* const* d_in, const int* in_sizes, int n_in,
                              void* d_out, int out_size, void* d_ws, size_t ws_size,
                              hipStream_t stream) {
  const float* px = (const float*)d_in[0];
  const float* lx = (const float*)d_in[1];
  const int* pei = (const int*)d_in[2];
  const int* lei = (const int*)d_in[3];
  const int* pb = (const int*)d_in[4];
  const int* lb = (const int*)d_in[5];
  const float* p1_Wl = (const float*)d_in[6];
  const float* p1_Wr = (const float*)d_in[7];
  const float* p1_att = (const float*)d_in[8];
  const float* p1_b = (const float*)d_in[9];
  const float* p2_Wl = (const float*)d_in[10];
  const float* p2_Wr = (const float*)d_in[11];
  const float* p2_att = (const float*)d_in[12];
  const float* p2_b = (const float*)d_in[13];
  const float* l1_Wl = (const float*)d_in[14];
  const float* l1_Wr = (const float*)d_in[15];
  const float* l1_att = (const float*)d_in[16];
  const float* l1_b = (const float*)d_in[17];
  const float* l2_Wl = (const float*)d_in[18];
  const float* l2_Wr = (const float*)d_in[19];
  const float* l2_att = (const float*)d_in[20];
  const float* l2_b = (const float*)d_in[21];
  const float* Wv = (const float*)d_in[26];
  const float* bv = (const float*)d_in[27];
  const float* Wo = (const float*)d_in[28];
  const float* bo = (const float*)d_in[29];
  const float* fc1w = (const float*)d_in[30];
  const float* fc1b = (const float*)d_in[31];
  const float* lng = (const float*)d_in[32];
  const float* lnb = (const float*)d_in[33];
  const float* fc2w = (const float*)d_in[34];
  const float* fc2b = (const float*)d_in[35];

  const int NPn = in_sizes[4];
  const int NLn = in_sizes[5];
  const int EPe = in_sizes[2] / 2;
  const int ELe = in_sizes[3] / 2;
  const int KP = in_sizes[0] / NPn;
  const int KL = in_sizes[1] / NLn;

  const int Nmax = NPn > NLn ? NPn : NLn;
  const int Emax = EPe > ELe ? EPe : ELe;
  size_t NF = (size_t)Nmax * 256;

  u16* XLh_p = (u16*)d_ws;
  u16* XRh_p = XLh_p + NF;
  u16* Ah_p = XRh_p + NF;
  u16* XLh_l = Ah_p + NF;
  u16* XRh_l = XLh_l + NF;
  u16* Ah_l = XRh_l + NF;
  u16* Wth = Ah_l + NF;  // 2 sides x 512*256
  u16* Wtl = Wth + 2 * 512 * 256;
  int* cnt = (int*)(Wtl + 2 * 512 * 256);
  int* cur = cnt + 2 * (size_t)Nmax;
  int* offs = cur + 2 * (size_t)Nmax;
  int* bsum = offs + 2 * (size_t)Nmax;
  int* csr = bsum + 512;
  int* cnt_l = cnt + Nmax;
  int* cur_l = cur + Nmax;
  int* offs_l = offs + Nmax;
  int* csr_l = csr + Emax;
  float* Wof = (float*)(csr + 2 * (size_t)Emax);  // 256x256 fold buffers
  float* W2f = Wof + 65536;
  float* bEff = W2f + 65536;

  const int nbp = (NPn + 255) / 256;
  const int nbl = (NLn + 255) / 256;
  const int nz = 2 * Nmax;
  const int zb = (nz + 255) / 256;
  const int linPer = (Nmax + 7) / 8;
  const int histB = (EPe + ELe + 255) / 256;

  // setup: zero cnt + weight split + layer-1 linear + fold stage 1 (fused)
  k_setup<<<zb + 1024 + 2 * linPer + 256, 256, 0, stream>>>(
      cnt, nz, p2_Wl, p2_Wr, l2_Wl, l2_Wr,
      Wth, Wtl, Wth + 512 * 256, Wtl + 512 * 256,
      px, KP, NPn, lx, KL, NLn, p1_Wl, p1_Wr, l1_Wl, l1_Wr,
      XLh_p, XRh_p, XLh_l, XRh_l, linPer, Wo, fc1w, Wof);
  // CSR build (+ fold stage 2)
  k_histb<<<histB + 257, 256, 0, stream>>>(pei, EPe, lei, ELe, cnt, cnt_l, histB,
                                           Wv, Wof, fc1w, bv, bo, fc1b, W2f, bEff);
  k_scan1b<<<nbp + nbl, 256, 0, stream>>>(cnt, NPn, cnt_l, NLn, nbp, offs, offs_l,
                                          cur, cur_l, bsum);
  k_scan2b<<<2, 256, 0, stream>>>(bsum, nbp, nbl);
  k_fillb<<<(EPe + ELe + 255) / 256, 256, 0, stream>>>(pei, EPe, lei, ELe, offs, offs_l,
                                                       bsum, cur, cur_l, csr, csr_l);
  // layer 1 gather (XCD-swizzled block map)
  k_gat_gather_b<2><<<dim3((Nmax + 3) / 4, 2), 256, 0, stream>>>(
      XLh_p, XRh_p, Ah_p, XLh_l, XRh_l, Ah_l,
      csr, offs, cnt, csr_l, offs_l, cnt_l, bsum,
      p1_att, p1_b, l1_att, l1_b, NPn, NLn);
  // layer 2 GEMM (XCD-grouped swizzle)
  {
    const int Rp = (NPn + 127) / 128;
    const int Rl = (NLn + 127) / 128;
    const int Rtot = Rp + Rl;
    k_mm_dual_b<<<32 * ((Rtot + 7) / 8), 256, 0, stream>>>(
        Ah_p, Ah_l, Wth, Wtl, Wth + 512 * 256, Wtl + 512 * 256,
        XLh_p, XRh_p, XLh_l, XRh_l, NPn, NLn, Rp, Rtot);
  }
  // layer 2 gather (XCD-swizzled block map)
  k_gat_gather_b<1><<<dim3((Nmax + 3) / 4, 2), 256, 0, stream>>>(
      XLh_p, XRh_p, Ah_p, XLh_l, XRh_l, Ah_l,
      csr, offs, cnt, csr_l, offs_l, cnt_l, bsum,
      p2_att, p2_b, l2_att, l2_b, NPn, NLn);
  // head (pool fused: reads Ah segments directly)
  k_head<<<256, 512, 0, stream>>>(Ah_p, Ah_l, pb, NPn, lb, NLn,
                                  fc1w, W2f, bEff, lng, lnb, fc2w, fc2b,
                                  (float*)d_out);
  (void)n_in; (void)out_size; (void)ws_size;
}